// Round 2
// baseline (894.382 us; speedup 1.0000x reference)
//
#include <hip/hip_runtime.h>
#include <math.h>

#define KCOMP 8
#define DDIM  16
#define UNR   4

// ws layout (floats):
//   [0, 2048)          Linv[k][i][c]  row-major, zero above diagonal
//   [2048, 2176)       b[k][i] = (Linv_k . mu_k)[i]
//   [2176, 2184)       c[k] = log(pi_k) + log_norm - logdet_k

__global__ __launch_bounds__(128) void prep_kernel(
    const float* __restrict__ mu, const float* __restrict__ sigma,
    const float* __restrict__ pi, float* __restrict__ ws)
{
    __shared__ float sLinv[KCOMP * DDIM * DDIM];
    const int tid = threadIdx.x;
    const int g = tid >> 4;   // component
    const int r = tid & 15;   // row (cholesky) / column (inverse)

    // Load row r of sigma_g into registers
    float a[DDIM];
    const float4* srow = (const float4*)(sigma + g * DDIM * DDIM + r * DDIM);
    float4 v0 = srow[0], v1 = srow[1], v2 = srow[2], v3 = srow[3];
    a[0]=v0.x;  a[1]=v0.y;  a[2]=v0.z;  a[3]=v0.w;
    a[4]=v1.x;  a[5]=v1.y;  a[6]=v1.z;  a[7]=v1.w;
    a[8]=v2.x;  a[9]=v2.y;  a[10]=v2.z; a[11]=v2.w;
    a[12]=v3.x; a[13]=v3.y; a[14]=v3.z; a[15]=v3.w;

    // Cholesky: lane r computes row r of L via width-16 shuffles.
    float l[DDIM];
    #pragma unroll
    for (int j = 0; j < DDIM; ++j) {
        float s = a[j];
        #pragma unroll
        for (int m = 0; m < j; ++m)
            s -= l[m] * __shfl(l[m], j, DDIM);
        float dj = sqrtf(__shfl(s, j, DDIM));
        float val;
        if (r == j)      val = dj;
        else if (r > j)  val = s / dj;
        else             val = 0.0f;
        l[j] = val;
    }

    // Invert L: lane r computes column r of Linv (forward substitution).
    float x[DDIM];
    #pragma unroll
    for (int i = 0; i < DDIM; ++i) {
        float t = (r == i) ? 1.0f : 0.0f;
        #pragma unroll
        for (int m = 0; m < i; ++m)
            t -= __shfl(l[m], i, DDIM) * x[m];
        x[i] = t / __shfl(l[i], i, DDIM);
    }

    // Store Linv row-major: lane r holds column r -> element [i][r]
    #pragma unroll
    for (int i = 0; i < DDIM; ++i) {
        sLinv[g * 256 + i * DDIM + r] = x[i];
        ws[g * 256 + i * DDIM + r]    = x[i];
    }
    __syncthreads();

    // b_r = sum_c Linv[r][c] * mu[c]
    float b = 0.0f;
    #pragma unroll
    for (int c = 0; c < DDIM; ++c)
        b += sLinv[g * 256 + r * DDIM + c] * mu[g * DDIM + c];
    ws[KCOMP * 256 + g * DDIM + r] = b;

    // logdet = sum_r log(L_rr); lane r's diagonal is l[r]
    float ld = logf(l[r]);
    #pragma unroll
    for (int off = 8; off >= 1; off >>= 1)
        ld += __shfl_xor(ld, off, DDIM);
    if (r == 0) {
        const float LOG2PI = 1.8378770664093454f;
        float ck = logf(pi[g]) - ld - 0.5f * DDIM * LOG2PI;
        ws[KCOMP * 256 + KCOMP * DDIM + g] = ck;
    }
}

__global__ __launch_bounds__(256) void energy_kernel(
    const float* __restrict__ z, const float* __restrict__ ws,
    float* __restrict__ out, int n)
{
    __shared__ float sL[KCOMP * DDIM * DDIM];
    __shared__ float sB[KCOMP * DDIM];
    __shared__ float sC[KCOMP];

    const int NPREP = KCOMP * 256 + KCOMP * DDIM + KCOMP;
    for (int t = threadIdx.x; t < NPREP; t += 256) {
        float v = ws[t];
        if (t < KCOMP * 256)                  sL[t] = v;
        else if (t < KCOMP * 256 + KCOMP*16)  sB[t - KCOMP * 256] = v;
        else                                  sC[t - KCOMP * 256 - KCOMP * 16] = v;
    }
    __syncthreads();

    const int stride = gridDim.x * 256;
    const int tid0 = blockIdx.x * 256 + threadIdx.x;

    float d[UNR][DDIM];
    int   s[UNR];
    bool  ok[UNR];
    #pragma unroll
    for (int u = 0; u < UNR; ++u) {
        s[u] = tid0 + u * stride;
        ok[u] = (s[u] < n);
        if (ok[u]) {
            const float4* zp = (const float4*)(z + (size_t)s[u] * DDIM);
            float4 w0 = zp[0], w1 = zp[1], w2 = zp[2], w3 = zp[3];
            d[u][0]=w0.x;  d[u][1]=w0.y;  d[u][2]=w0.z;  d[u][3]=w0.w;
            d[u][4]=w1.x;  d[u][5]=w1.y;  d[u][6]=w1.z;  d[u][7]=w1.w;
            d[u][8]=w2.x;  d[u][9]=w2.y;  d[u][10]=w2.z; d[u][11]=w2.w;
            d[u][12]=w3.x; d[u][13]=w3.y; d[u][14]=w3.z; d[u][15]=w3.w;
        } else {
            #pragma unroll
            for (int c = 0; c < DDIM; ++c) d[u][c] = 0.0f;
        }
    }

    // log-prob per component, tracked with running max for log-sum-exp
    float lp[KCOMP][UNR];
    float mx[UNR];
    #pragma unroll
    for (int u = 0; u < UNR; ++u) mx[u] = -1e30f;

    #pragma unroll
    for (int k = 0; k < KCOMP; ++k) {
        const float* Lk = &sL[k * 256];
        float maha[UNR];
        #pragma unroll
        for (int u = 0; u < UNR; ++u) maha[u] = 0.0f;

        #pragma unroll
        for (int i = 0; i < DDIM; ++i) {
            float bi = sB[k * DDIM + i];
            float y[UNR];
            #pragma unroll
            for (int u = 0; u < UNR; ++u) y[u] = -bi;
            #pragma unroll
            for (int c = 0; c <= i; ++c) {
                float lv = Lk[i * DDIM + c];
                #pragma unroll
                for (int u = 0; u < UNR; ++u) y[u] = fmaf(lv, d[u][c], y[u]);
            }
            #pragma unroll
            for (int u = 0; u < UNR; ++u) maha[u] = fmaf(y[u], y[u], maha[u]);
        }
        float ck = sC[k];
        #pragma unroll
        for (int u = 0; u < UNR; ++u) {
            lp[k][u] = fmaf(-0.5f, maha[u], ck);
            mx[u] = fmaxf(mx[u], lp[k][u]);
        }
    }

    // energy = -(mx + log(sum_k exp(lp_k - mx)))  -- always finite
    float dens[UNR];
    #pragma unroll
    for (int u = 0; u < UNR; ++u) dens[u] = 0.0f;
    #pragma unroll
    for (int k = 0; k < KCOMP; ++k) {
        #pragma unroll
        for (int u = 0; u < UNR; ++u)
            dens[u] += expf(lp[k][u] - mx[u]);
    }

    #pragma unroll
    for (int u = 0; u < UNR; ++u)
        if (ok[u]) out[s[u]] = -(mx[u] + logf(dens[u]));
}

extern "C" void kernel_launch(void* const* d_in, const int* in_sizes, int n_in,
                              void* d_out, int out_size, void* d_ws, size_t ws_size,
                              hipStream_t stream) {
    const float* mu    = (const float*)d_in[0];
    const float* sigma = (const float*)d_in[1];
    const float* z     = (const float*)d_in[2];
    const float* pi    = (const float*)d_in[3];
    float* ws  = (float*)d_ws;
    float* out = (float*)d_out;

    const int n = in_sizes[2] / DDIM;   // number of samples (524288)

    prep_kernel<<<1, 128, 0, stream>>>(mu, sigma, pi, ws);

    const int blocks = (n + 256 * UNR - 1) / (256 * UNR);   // 512
    energy_kernel<<<blocks, 256, 0, stream>>>(z, ws, out, n);
}

// Round 3
// 110.640 us; speedup vs baseline: 8.0837x; 8.0837x over previous
//
#include <hip/hip_runtime.h>
#include <math.h>

#define KCOMP 8
#define DDIM  16
#define UNR   4

// ws layout (floats):
//   [0, 2048)          Linv[k][i][c]  row-major, zero above diagonal
//   [2048, 2176)       b[k][i] = (Linv_k . mu_k)[i]
//   [2176, 2184)       c[k] = log(pi_k) + log_norm - logdet_k

__global__ __launch_bounds__(128) void prep_kernel(
    const float* __restrict__ mu, const float* __restrict__ sigma,
    const float* __restrict__ pi, float* __restrict__ ws)
{
    __shared__ float sLinv[KCOMP * DDIM * DDIM];
    const int tid = threadIdx.x;
    const int g = tid >> 4;   // component
    const int r = tid & 15;   // row (cholesky) / column (inverse)

    // Load row r of sigma_g into registers
    float a[DDIM];
    const float4* srow = (const float4*)(sigma + g * DDIM * DDIM + r * DDIM);
    float4 v0 = srow[0], v1 = srow[1], v2 = srow[2], v3 = srow[3];
    a[0]=v0.x;  a[1]=v0.y;  a[2]=v0.z;  a[3]=v0.w;
    a[4]=v1.x;  a[5]=v1.y;  a[6]=v1.z;  a[7]=v1.w;
    a[8]=v2.x;  a[9]=v2.y;  a[10]=v2.z; a[11]=v2.w;
    a[12]=v3.x; a[13]=v3.y; a[14]=v3.z; a[15]=v3.w;

    // Cholesky: lane r computes row r of L via width-16 shuffles.
    float l[DDIM];
    #pragma unroll
    for (int j = 0; j < DDIM; ++j) {
        float s = a[j];
        #pragma unroll
        for (int m = 0; m < j; ++m)
            s -= l[m] * __shfl(l[m], j, DDIM);
        float dj = sqrtf(__shfl(s, j, DDIM));
        float val;
        if (r == j)      val = dj;
        else if (r > j)  val = s / dj;
        else             val = 0.0f;
        l[j] = val;
    }

    // Invert L: lane r computes column r of Linv (forward substitution).
    float x[DDIM];
    #pragma unroll
    for (int i = 0; i < DDIM; ++i) {
        float t = (r == i) ? 1.0f : 0.0f;
        #pragma unroll
        for (int m = 0; m < i; ++m)
            t -= __shfl(l[m], i, DDIM) * x[m];
        x[i] = t / __shfl(l[i], i, DDIM);
    }

    // Store Linv row-major: lane r holds column r -> element [i][r]
    #pragma unroll
    for (int i = 0; i < DDIM; ++i) {
        sLinv[g * 256 + i * DDIM + r] = x[i];
        ws[g * 256 + i * DDIM + r]    = x[i];
    }
    __syncthreads();

    // b_r = sum_c Linv[r][c] * mu[c]
    float b = 0.0f;
    #pragma unroll
    for (int c = 0; c < DDIM; ++c)
        b += sLinv[g * 256 + r * DDIM + c] * mu[g * DDIM + c];
    ws[KCOMP * 256 + g * DDIM + r] = b;

    // logdet = sum_r log(L_rr); lane r's diagonal is l[r]
    float ld = logf(l[r]);
    #pragma unroll
    for (int off = 8; off >= 1; off >>= 1)
        ld += __shfl_xor(ld, off, DDIM);
    if (r == 0) {
        const float LOG2PI = 1.8378770664093454f;
        float ck = logf(pi[g]) - ld - 0.5f * DDIM * LOG2PI;
        ws[KCOMP * 256 + KCOMP * DDIM + g] = ck;
    }
}

__global__ __launch_bounds__(256) void energy_kernel(
    const float* __restrict__ z, const float* __restrict__ ws,
    float* __restrict__ out, int n)
{
    // 16B-aligned so contiguous triangle rows vectorize to ds_read_b64/b128
    __shared__ __align__(16) float sL[KCOMP * DDIM * DDIM];
    __shared__ __align__(16) float sB[KCOMP * DDIM];
    __shared__ float sC[KCOMP];

    const int NPREP = KCOMP * 256 + KCOMP * DDIM + KCOMP;
    for (int t = threadIdx.x; t < NPREP; t += 256) {
        float v = ws[t];
        if (t < KCOMP * 256)                  sL[t] = v;
        else if (t < KCOMP * 256 + KCOMP*16)  sB[t - KCOMP * 256] = v;
        else                                  sC[t - KCOMP * 256 - KCOMP * 16] = v;
    }
    __syncthreads();

    const int stride = gridDim.x * 256;
    const int tid0 = blockIdx.x * 256 + threadIdx.x;

    float d[UNR][DDIM];
    int   s[UNR];
    bool  ok[UNR];
    #pragma unroll
    for (int u = 0; u < UNR; ++u) {
        s[u] = tid0 + u * stride;
        ok[u] = (s[u] < n);
        if (ok[u]) {
            const float4* zp = (const float4*)(z + (size_t)s[u] * DDIM);
            float4 w0 = zp[0], w1 = zp[1], w2 = zp[2], w3 = zp[3];
            d[u][0]=w0.x;  d[u][1]=w0.y;  d[u][2]=w0.z;  d[u][3]=w0.w;
            d[u][4]=w1.x;  d[u][5]=w1.y;  d[u][6]=w1.z;  d[u][7]=w1.w;
            d[u][8]=w2.x;  d[u][9]=w2.y;  d[u][10]=w2.z; d[u][11]=w2.w;
            d[u][12]=w3.x; d[u][13]=w3.y; d[u][14]=w3.z; d[u][15]=w3.w;
        } else {
            #pragma unroll
            for (int c = 0; c < DDIM; ++c) d[u][c] = 0.0f;
        }
    }

    // Online log-sum-exp state (no lp[][] array -> no register blow-up)
    float mx[UNR], dens[UNR];
    #pragma unroll
    for (int u = 0; u < UNR; ++u) { mx[u] = -1e30f; dens[u] = 0.0f; }

    // CRITICAL: do NOT unroll over components — keeps the live set to one
    // component's streamed Lk values (round-2's full unroll spilled 800 B/sample).
    #pragma unroll 1
    for (int k = 0; k < KCOMP; ++k) {
        const float* Lk = &sL[k * 256];
        float maha[UNR];
        #pragma unroll
        for (int u = 0; u < UNR; ++u) maha[u] = 0.0f;

        #pragma unroll
        for (int i = 0; i < DDIM; ++i) {
            float bi = sB[k * DDIM + i];
            float y[UNR];
            #pragma unroll
            for (int u = 0; u < UNR; ++u) y[u] = -bi;
            #pragma unroll
            for (int c = 0; c <= i; ++c) {
                float lv = Lk[i * DDIM + c];
                #pragma unroll
                for (int u = 0; u < UNR; ++u) y[u] = fmaf(lv, d[u][c], y[u]);
            }
            #pragma unroll
            for (int u = 0; u < UNR; ++u) maha[u] = fmaf(y[u], y[u], maha[u]);
        }
        float ck = sC[k];
        #pragma unroll
        for (int u = 0; u < UNR; ++u) {
            float lp = fmaf(-0.5f, maha[u], ck);
            float nm = fmaxf(mx[u], lp);
            dens[u] = dens[u] * __expf(mx[u] - nm) + __expf(lp - nm);
            mx[u] = nm;
        }
    }

    #pragma unroll
    for (int u = 0; u < UNR; ++u)
        if (ok[u]) out[s[u]] = -(mx[u] + __logf(dens[u]));
}

extern "C" void kernel_launch(void* const* d_in, const int* in_sizes, int n_in,
                              void* d_out, int out_size, void* d_ws, size_t ws_size,
                              hipStream_t stream) {
    const float* mu    = (const float*)d_in[0];
    const float* sigma = (const float*)d_in[1];
    const float* z     = (const float*)d_in[2];
    const float* pi    = (const float*)d_in[3];
    float* ws  = (float*)d_ws;
    float* out = (float*)d_out;

    const int n = in_sizes[2] / DDIM;   // number of samples (524288)

    prep_kernel<<<1, 128, 0, stream>>>(mu, sigma, pi, ws);

    const int blocks = (n + 256 * UNR - 1) / (256 * UNR);   // 512
    energy_kernel<<<blocks, 256, 0, stream>>>(z, ws, out, n);
}

// Round 4
// 106.410 us; speedup vs baseline: 8.4051x; 1.0397x over previous
//
#include <hip/hip_runtime.h>
#include <math.h>

#define KCOMP 8
#define DDIM  16

typedef __attribute__((ext_vector_type(8))) short bf16x8;
typedef __attribute__((ext_vector_type(4))) float f32x4;

// fp32 -> bf16 bits, round-to-nearest-even (inputs are finite; no NaN handling)
static __device__ __forceinline__ short f2bf(float f) {
    unsigned u = __float_as_uint(f);
    unsigned r = (u + 0x7FFFu + ((u >> 16) & 1u)) >> 16;
    return (short)r;
}

// ws layout (floats):
//   [0, 2048)          Linv[k][i][c]  row-major, zero above diagonal
//   [2048, 2176)       b[k][i] = (Linv_k . mu_k)[i]
//   [2176, 2184)       c[k] = log(pi_k) + log_norm - logdet_k

__global__ __launch_bounds__(128) void prep_kernel(
    const float* __restrict__ mu, const float* __restrict__ sigma,
    const float* __restrict__ pi, float* __restrict__ ws)
{
    __shared__ float sLinv[KCOMP * DDIM * DDIM];
    const int tid = threadIdx.x;
    const int g = tid >> 4;   // component
    const int r = tid & 15;   // row (cholesky) / column (inverse)

    float a[DDIM];
    const float4* srow = (const float4*)(sigma + g * DDIM * DDIM + r * DDIM);
    float4 v0 = srow[0], v1 = srow[1], v2 = srow[2], v3 = srow[3];
    a[0]=v0.x;  a[1]=v0.y;  a[2]=v0.z;  a[3]=v0.w;
    a[4]=v1.x;  a[5]=v1.y;  a[6]=v1.z;  a[7]=v1.w;
    a[8]=v2.x;  a[9]=v2.y;  a[10]=v2.z; a[11]=v2.w;
    a[12]=v3.x; a[13]=v3.y; a[14]=v3.z; a[15]=v3.w;

    // Cholesky: lane r computes row r of L via width-16 shuffles.
    float l[DDIM];
    #pragma unroll
    for (int j = 0; j < DDIM; ++j) {
        float s = a[j];
        #pragma unroll
        for (int m = 0; m < j; ++m)
            s -= l[m] * __shfl(l[m], j, DDIM);
        float dj = sqrtf(__shfl(s, j, DDIM));
        float val;
        if (r == j)      val = dj;
        else if (r > j)  val = s / dj;
        else             val = 0.0f;
        l[j] = val;
    }

    // Invert L: lane r computes column r of Linv (forward substitution).
    float x[DDIM];
    #pragma unroll
    for (int i = 0; i < DDIM; ++i) {
        float t = (r == i) ? 1.0f : 0.0f;
        #pragma unroll
        for (int m = 0; m < i; ++m)
            t -= __shfl(l[m], i, DDIM) * x[m];
        x[i] = t / __shfl(l[i], i, DDIM);
    }

    #pragma unroll
    for (int i = 0; i < DDIM; ++i) {
        sLinv[g * 256 + i * DDIM + r] = x[i];
        ws[g * 256 + i * DDIM + r]    = x[i];
    }
    __syncthreads();

    float b = 0.0f;
    #pragma unroll
    for (int c = 0; c < DDIM; ++c)
        b += sLinv[g * 256 + r * DDIM + c] * mu[g * DDIM + c];
    ws[KCOMP * 256 + g * DDIM + r] = b;

    float ld = logf(l[r]);
    #pragma unroll
    for (int off = 8; off >= 1; off >>= 1)
        ld += __shfl_xor(ld, off, DDIM);
    if (r == 0) {
        const float LOG2PI = 1.8378770664093454f;
        float ck = logf(pi[g]) - ld - 0.5f * DDIM * LOG2PI;
        ws[KCOMP * 256 + KCOMP * DDIM + g] = ck;
    }
}

// MFMA formulation: Y_k = Linv_k z - b_k = z~ . W_k^T with z~ = [z, 1, 0...]
// (K padded 17->32). One mfma_f32_16x16x32_bf16 per (component, 16-sample
// tile): A = W_k (M=16 rows i, K=32), B = z~^T (K=32, N=16 samples).
// Verified layouts: A[m=lane&15][k=quad*8+j], B[k=quad*8+j][n=lane&15],
// D: col=lane&15, row=quad*4+reg.
__global__ __launch_bounds__(256) void energy_kernel(
    const float* __restrict__ z, const float* __restrict__ ws,
    float* __restrict__ out, int n)
{
    const int lane = threadIdx.x & 63;
    const int m    = lane & 15;
    const int quad = lane >> 4;
    const int wave = (blockIdx.x * blockDim.x + threadIdx.x) >> 6;

    // Preload all 8 A fragments (W_k): 32 VGPRs total, reused for all samples.
    bf16x8 afrag[KCOMP];
    #pragma unroll
    for (int k = 0; k < KCOMP; ++k) {
        bf16x8 a = {0,0,0,0,0,0,0,0};
        if (quad < 2) {
            const float* Lrow = ws + k * 256 + m * DDIM + quad * 8;
            #pragma unroll
            for (int j = 0; j < 8; ++j) a[j] = f2bf(Lrow[j]);
        } else if (quad == 2) {
            a[0] = f2bf(-ws[KCOMP * 256 + k * DDIM + m]);   // c==16: -b_k[i]
        }
        afrag[k] = a;
    }
    float ck[KCOMP];
    #pragma unroll
    for (int k = 0; k < KCOMP; ++k)
        ck[k] = ws[KCOMP * 256 + KCOMP * DDIM + k];

    const f32x4 zero4 = {0.f, 0.f, 0.f, 0.f};
    const int SPW = 256;                 // samples per wave
    const int base = wave * SPW;

    #pragma unroll 1
    for (int it = 0; it < SPW / 64; ++it) {
        const int tb = base + it * 64;   // 64 samples = 4 tiles of 16
        float en[4];
        #pragma unroll
        for (int t = 0; t < 4; ++t) {
            // Build B fragment for tile t
            bf16x8 bfrag = {0,0,0,0,0,0,0,0};
            const int s = tb + t * 16 + m;
            if (quad < 2) {
                if (s < n) {
                    const float* zp = z + (size_t)s * DDIM + quad * 8;
                    #pragma unroll
                    for (int j = 0; j < 8; ++j) bfrag[j] = f2bf(zp[j]);
                }
            } else if (quad == 2) {
                bfrag[0] = (short)0x3F80;   // bf16(1.0) bias row
            }

            // 8 independent MFMAs (one per mixture component)
            f32x4 dres[KCOMP];
            #pragma unroll
            for (int k = 0; k < KCOMP; ++k)
                dres[k] = __builtin_amdgcn_mfma_f32_16x16x32_bf16(
                              afrag[k], bfrag, zero4, 0, 0, 0);

            // Epilogue: maha_k = ||Y||^2 (4 local squares + cross-quad sum),
            // then online log-sum-exp over k.
            float mx = -1e30f, dens = 0.0f;
            #pragma unroll
            for (int k = 0; k < KCOMP; ++k) {
                f32x4 d4 = dres[k];
                float p = d4[0]*d4[0] + d4[1]*d4[1] + d4[2]*d4[2] + d4[3]*d4[3];
                p += __shfl_xor(p, 16, 64);
                p += __shfl_xor(p, 32, 64);
                float lp = fmaf(-0.5f, p, ck[k]);
                float nm = fmaxf(mx, lp);
                dens = dens * __expf(mx - nm) + __expf(lp - nm);
                mx = nm;
            }
            en[t] = -(mx + __logf(dens));
        }
        // Every lane holds energy for sample (t*16 + m) of each tile t;
        // lane writes tile (quad) -> one coalesced 256B wave store.
        float e = en[0];
        e = (quad == 1) ? en[1] : e;
        e = (quad == 2) ? en[2] : e;
        e = (quad == 3) ? en[3] : e;
        const int so = tb + quad * 16 + m;
        if (so < n) out[so] = e;
    }
}

extern "C" void kernel_launch(void* const* d_in, const int* in_sizes, int n_in,
                              void* d_out, int out_size, void* d_ws, size_t ws_size,
                              hipStream_t stream) {
    const float* mu    = (const float*)d_in[0];
    const float* sigma = (const float*)d_in[1];
    const float* z     = (const float*)d_in[2];
    const float* pi    = (const float*)d_in[3];
    float* ws  = (float*)d_ws;
    float* out = (float*)d_out;

    const int n = in_sizes[2] / DDIM;   // number of samples (524288)

    prep_kernel<<<1, 128, 0, stream>>>(mu, sigma, pi, ws);

    // 256 threads = 4 waves/block, 256 samples/wave -> 1024 samples/block
    const int blocks = (n + 1023) / 1024;   // 512
    energy_kernel<<<blocks, 256, 0, stream>>>(z, ws, out, n);
}